// Round 8
// baseline (112.335 us; speedup 1.0000x reference)
//
#include <hip/hip_runtime.h>
#include <math.h>

#define IC 64
#define OC 128
#define HH 56
#define WW 56
#define BATCH 16
#define HP 58              // padded spatial
#define HW (HH*WW)         // 3136
#define NPIX (BATCH*HW)    // 50176
#define SPAN 576
#define TSIZE 8
#define VBANDS 28          // 2-row bands per image
#define VBLOCKS (BATCH*VBANDS)   // 448 votepad blocks
#define W2BASE  VBLOCKS          // 448
#define BORDBASE (VBLOCKS + OC)  // 576
#define NBLK1 (BORDBASE + BATCH) // 592

typedef unsigned short ushort_t;
typedef unsigned int uint_t;
typedef __attribute__((ext_vector_type(8))) __bf16 bf16x8;
typedef __attribute__((ext_vector_type(4))) float f32x4;

__device__ __forceinline__ ushort_t bf16_rne(float f) {
  uint_t u = __builtin_bit_cast(uint_t, f);
  u += 0x7FFFu + ((u >> 16) & 1u);
  return (ushort_t)(u >> 16);
}

// ---- kernel 1: fused prep, role-split by blockIdx ---------------------------
// [0,448):   votepad — per 2-row band: t into LDS (halo), vote hist, AND
//            bf16 conversion of the middle rows -> coalesced NHWC xpad store
// [448,576): w2row — per-row dot/norm -> rbucket + bf16 (tap,c)-major repack
// [576,592): border — zero the xpad halo ring per image
__global__ __launch_bounds__(256)
void prep_kernel(const float* __restrict__ x, const float* __restrict__ kernels,
                 const float* __restrict__ a, const float* __restrict__ bptr,
                 ushort_t* __restrict__ xpad, ushort_t* __restrict__ w2,
                 int* __restrict__ rbucket, int* __restrict__ hist_partial) {
  __shared__ float tl[224 * 9];       // 8064 B
  __shared__ ushort_t lx[112 * 66];   // 14784 B (33-dword stride: conflict-free)
  __shared__ int hist[TSIZE];
  __shared__ float red0[256], red1[256];
  const int bx = blockIdx.x, t = threadIdx.x;

  if (bx < VBLOCKS) {
    // ---------------- votepad role ----------------
    const int b = bx / VBANDS, band = bx % VBANDS;
    const int r0 = band * 2;
    if (t < TSIZE) hist[t] = 0;
    if (t < 224) {
      const int prow = r0 - 1 + t / 56;   // -1 .. 56 (1-row halo each side)
      const int col = t % 56;
      const bool inr = ((unsigned)prow < (unsigned)HH);
      const bool mid = (t >= 56 && t < 168);
      const float* xb = x + (size_t)b * IC * HW + (inr ? prow * WW + col : 0);
      ushort_t* lxp = lx + (mid ? (t - 56) : 0) * 66;
      float t9[9] = {0, 0, 0, 0, 0, 0, 0, 0, 0};
      #pragma unroll 8
      for (int c = 0; c < IC; ++c) {
        float xv = inr ? xb[(size_t)c * HW] : 0.0f;
        #pragma unroll
        for (int tap = 0; tap < 9; ++tap) t9[tap] += a[c * 9 + tap] * xv;
        if (mid) lxp[c] = bf16_rne(xv);
      }
      #pragma unroll
      for (int tap = 0; tap < 9; ++tap) tl[t * 9 + tap] = t9[tap];
    }
    __syncthreads();
    if (t < 112) {
      int lr = t / 56, col = t % 56;
      float v = 0.0f;
      #pragma unroll
      for (int kh = 0; kh < 3; ++kh) {
        int gr = r0 + lr - 1 + kh;
        #pragma unroll
        for (int kw = 0; kw < 3; ++kw) {
          int cc = col - 1 + kw;
          if ((unsigned)gr < (unsigned)HH && (unsigned)cc < (unsigned)WW)
            v += tl[((lr + kh) * 56 + cc) * 9 + (kh * 3 + kw)];
        }
      }
      float tail = 0.5f * (a[576] + a[577] + a[578] + a[579] + a[580]);
      int hi = (int)floorf((v + tail + bptr[0]) / 2.5f);
      int r = hi % TSIZE;
      if (r < 0) r = -r;
      atomicAdd(&hist[r], 1);       // LDS atomic, 8 bins
    }
    // coalesced xpad store: 112 px x 32 dwords; lanes sweep the channel dim
    {
      const uint_t* lxu = (const uint_t*)lx;
      uint_t* xp = (uint_t*)xpad;
      #pragma unroll
      for (int j = 0; j < 14; ++j) {
        int idx = j * 256 + t;
        int px = idx >> 5, cp = idx & 31;
        int lr = px / 56, c0 = px % 56;
        int y = r0 + 1 + lr, xw = c0 + 1;
        xp[(((size_t)(b * HP + y)) * HP + xw) * 32 + cp] = lxu[px * 33 + cp];
      }
    }
    __syncthreads();
    if (t < TSIZE) hist_partial[bx * TSIZE + t] = hist[t];
  } else if (bx < BORDBASE) {
    // ---------------- w2row role ----------------
    const int r = bx - W2BASE;
    const float* row = kernels + (size_t)r * SPAN;
    float d = 0.0f, n2 = 0.0f;
    #pragma unroll
    for (int k0 = 0; k0 < 3; ++k0) {
      int k = k0 * 256 + t;
      if (k < SPAN) { float kv = row[k]; d += kv * a[k]; n2 += kv * kv; }
    }
    red0[t] = d; red1[t] = n2;
    __syncthreads();
    for (int s = 128; s > 0; s >>= 1) {
      if (t < s) { red0[t] += red0[t + s]; red1[t] += red1[t + s]; }
      __syncthreads();
    }
    if (t == 0) {
      float hk = red0[0], p = red1[0];
      #pragma unroll
      for (int i = 0; i < 5; ++i) { hk += p * a[SPAN + i]; p = p * p; }
      int hi = (int)floorf((hk + bptr[0]) / 2.5f);
      int rr = hi % TSIZE;
      if (rr < 0) rr = -rr;
      rbucket[r] = rr;
    }
    #pragma unroll
    for (int j0 = 0; j0 < 3; ++j0) {
      int j = j0 * 256 + t;
      if (j < SPAN) {
        int tap = j >> 6, c = j & 63;
        w2[(size_t)r * SPAN + j] = bf16_rne(row[c * 9 + tap]);
      }
    }
  } else {
    // ---------------- border-zero role: halo ring of xpad (disjoint addrs) --
    const int ib = bx - BORDBASE;
    uint_t* xp = (uint_t*)xpad + (size_t)ib * HP * HP * 32;
    for (int j = t; j < 7296; j += 256) {   // 228 border px * 32 dwords
      int px = j >> 5, cp = j & 31;
      int y, xw;
      if (px < 58) { y = 0; xw = px; }
      else if (px < 116) { y = 57; xw = px - 58; }
      else { int k = px - 116; y = 1 + (k >> 1); xw = (k & 1) * 57; }
      xp[((size_t)y * HP + xw) * 32 + cp] = 0;
    }
  }
}

// ---- kernel 2: implicit GEMM, 128x64 tile, BK=64 (one tap) ------------------
__global__ __launch_bounds__(256, 4)
void gemm_kernel(const ushort_t* __restrict__ w2, const ushort_t* __restrict__ xpad,
                 const int* __restrict__ hist_partial, const int* __restrict__ rbucket,
                 float* __restrict__ out) {
  __shared__ ushort_t As[128 * 64];   // 16 KB
  __shared__ ushort_t Bs[64 * 64];    //  8 KB
  __shared__ float factor_s[OC];
  __shared__ int counts_s[TSIZE];
  __shared__ int cnt_w[4];
  const int tid = threadIdx.x;
  const int wave = tid >> 6, lane = tid & 63;
  const int n0 = blockIdx.x * 64;
  const int wm = wave * 32;

  const int srow = lane >> 3;
  const int sch = (lane & 7) ^ srow;

  int agbase[4], bgbase[2];
  #pragma unroll
  for (int i = 0; i < 4; ++i) {
    int row = wm + i * 8 + srow;
    agbase[i] = row * SPAN + sch * 8;
  }
  #pragma unroll
  for (int i = 0; i < 2; ++i) {
    int brow = wave * 16 + i * 8 + srow;
    int n = n0 + brow;
    int b = n / HW;
    int rem = n % HW;
    int h = rem / WW, w = rem % WW;
    bgbase[i] = ((b * HP + h) * HP + w) * IC + sch * 8;
  }

  f32x4 acc[2][4] = {};

  for (int tap = 0; tap < 9; ++tap) {
    const int kh = tap / 3, kw = tap % 3;
    const int toffA = tap * 64;
    const int toffB = (kh * HP + kw) * IC;
    __syncthreads();
    #pragma unroll
    for (int i = 0; i < 4; ++i)
      __builtin_amdgcn_global_load_lds(
          (const __attribute__((address_space(1))) void*)(w2 + agbase[i] + toffA),
          (__attribute__((address_space(3))) void*)(As + (wm + i * 8) * 64), 16, 0, 0);
    #pragma unroll
    for (int i = 0; i < 2; ++i)
      __builtin_amdgcn_global_load_lds(
          (const __attribute__((address_space(1))) void*)(xpad + bgbase[i] + toffB),
          (__attribute__((address_space(3))) void*)(Bs + (wave * 16 + i * 8) * 64), 16, 0, 0);
    __syncthreads();
    #pragma unroll
    for (int kk = 0; kk < 2; ++kk) {
      const int jf = kk * 4 + (lane >> 4);
      bf16x8 af[2], bfr[4];
      #pragma unroll
      for (int m = 0; m < 2; ++m) {
        int row = wm + m * 16 + (lane & 15);
        int slot = row * 8 + (jf ^ (row & 7));
        af[m] = *(const bf16x8*)(As + slot * 8);
      }
      #pragma unroll
      for (int n = 0; n < 4; ++n) {
        int col = n * 16 + (lane & 15);
        int slot = col * 8 + (jf ^ (col & 7));
        bfr[n] = *(const bf16x8*)(Bs + slot * 8);
      }
      #pragma unroll
      for (int m = 0; m < 2; ++m)
        #pragma unroll
        for (int n = 0; n < 4; ++n)
          acc[m][n] = __builtin_amdgcn_mfma_f32_16x16x32_bf16(af[m], bfr[n], acc[m][n], 0, 0, 0);
    }
  }

  // ---- reduce hist_partial -> counts_s ----
  if (tid < TSIZE) counts_s[tid] = 0;
  __syncthreads();
  {
    int bin = tid >> 5;
    int s = 0;
    for (int k = (tid & 31); k < VBLOCKS; k += 32) s += hist_partial[k * TSIZE + bin];
    atomicAdd(&counts_s[bin], s);
  }
  __syncthreads();
  int best = counts_s[0], bi = 0;
  #pragma unroll
  for (int i = 1; i < TSIZE; ++i) { int c = counts_s[i]; if (c > best) { best = c; bi = i; } }
  int isin = (tid < OC) ? ((rbucket[tid] == bi) ? 1 : 0) : 0;
  unsigned long long bal = __ballot(isin != 0);
  if (lane == 0) cnt_w[wave] = __popcll(bal);
  __syncthreads();
  int cnt = cnt_w[0] + cnt_w[1] + cnt_w[2] + cnt_w[3];
  if (tid < OC)
    factor_s[tid] = (cnt > 0) ? (isin ? 128.0f / (float)cnt : 0.0f) : 1.0f;
  __syncthreads();

  #pragma unroll
  for (int n = 0; n < 4; ++n) {
    int np = n0 + n * 16 + (lane & 15);
    int b = np / HW;
    int rem = np % HW;
    float* obase = out + ((size_t)b * OC) * HW + rem;
    #pragma unroll
    for (int m = 0; m < 2; ++m) {
      int ocb = wm + m * 16 + (lane >> 4) * 4;
      #pragma unroll
      for (int r = 0; r < 4; ++r) {
        obase[(size_t)(ocb + r) * HW] = acc[m][n][r] * factor_s[ocb + r];
      }
    }
  }
}

extern "C" void kernel_launch(void* const* d_in, const int* in_sizes, int n_in,
                              void* d_out, int out_size, void* d_ws, size_t ws_size,
                              hipStream_t stream) {
  (void)in_sizes; (void)n_in; (void)out_size; (void)ws_size;
  const float* x = (const float*)d_in[0];       // [16,64,56,56]
  const float* kernels = (const float*)d_in[1]; // [128,576]
  const float* a = (const float*)d_in[2];       // [581]
  const float* b = (const float*)d_in[3];       // scalar
  float* out = (float*)d_out;                   // [16,128,56,56] fp32

  char* ws = (char*)d_ws;
  int* rbucket = (int*)ws;                      // 512 B
  int* hist_partial = (int*)(ws + 512);         // 448*8*4 = 14336 B
  ushort_t* w2 = (ushort_t*)(ws + 16384);       // 147456 B
  ushort_t* xpad = (ushort_t*)(ws + 16384 + 147456); // 6889472 B

  prep_kernel<<<NBLK1, 256, 0, stream>>>(x, kernels, a, b, xpad, w2, rbucket, hist_partial);
  gemm_kernel<<<NPIX / 64, 256, 0, stream>>>(w2, xpad, hist_partial, rbucket, out);
}